// Round 3
// baseline (7286.420 us; speedup 1.0000x reference)
//
#include <hip/hip_runtime.h>
#include <hip/hip_bf16.h>
#include <math.h>

#define Bz 64
#define Tz 256
#define Dz 512
#define Hz 1024
#define G3 3072
#define NBK 64      // blocks in persistent recurrence kernel

typedef short bf16x8 __attribute__((ext_vector_type(8)));
typedef float f32x4 __attribute__((ext_vector_type(4)));

__device__ __forceinline__ float sigm(float x){ return 1.0f/(1.0f+expf(-x)); }

__device__ __forceinline__ unsigned short f2b(float f){
  union{float f;unsigned u;}v; v.f=f;
  unsigned r = v.u + 0x7FFFu + ((v.u>>16)&1u);
  return (unsigned short)(r>>16);
}
__device__ __forceinline__ float b2f(unsigned short s){
  union{unsigned u;float f;}v; v.u = ((unsigned)s)<<16; return v.f;
}
__device__ __forceinline__ unsigned pk2(float a, float b){
  return (unsigned)f2b(a) | ((unsigned)f2b(b)<<16);
}

// ---- coherent (agent-scope, sc1; no-fence) access helpers ----
__device__ __forceinline__ unsigned long long cld64(const void* p){
  return __hip_atomic_load((const unsigned long long*)p, __ATOMIC_RELAXED, __HIP_MEMORY_SCOPE_AGENT);
}
__device__ __forceinline__ void cst64(void* p, unsigned long long v){
  __hip_atomic_store((unsigned long long*)p, v, __ATOMIC_RELAXED, __HIP_MEMORY_SCOPE_AGENT);
}
__device__ __forceinline__ float2 cldf2(const float* p){
  union { unsigned long long u; float2 f; } U; U.u = cld64(p); return U.f;
}
__device__ __forceinline__ void cstf2(float* p, float a, float b){
  union { unsigned long long u; float2 f; } U; U.f = make_float2(a,b); cst64(p, U.u);
}
__device__ __forceinline__ bf16x8 cldb8(const unsigned short* p){
  union { unsigned long long u[2]; bf16x8 v; } U;
  U.u[0] = cld64(p); U.u[1] = cld64(p+4);
  return U.v;
}

// ---- single-hop grid barrier: per-block arrival flags, every block's
// wave 0 polls all 64 flags directly (no block-0 aggregation / rebroadcast).
// Critical path: data drain -> flag store -> remote detection (one hop).
__device__ __forceinline__ void gbar(int* flags, int ph) {
  __syncthreads();   // drains each wave's vmcnt -> all sc1 data stores agent-visible
  if (threadIdx.x == 0)
    __hip_atomic_store(flags + blockIdx.x, ph, __ATOMIC_RELAXED, __HIP_MEMORY_SCOPE_AGENT);
  if (threadIdx.x < 64) {
    while (!__all(__hip_atomic_load(flags + threadIdx.x, __ATOMIC_RELAXED,
                                    __HIP_MEMORY_SCOPE_AGENT) >= ph))
      __builtin_amdgcn_s_sleep(1);
  }
  __syncthreads();
}

// ---------------- f32 skinny GEMM core (kP only, tiny) ----------------
#define KCHUNK 128
#define LDA 132
template<int COLS, int KDIM>
__device__ __forceinline__ void gemm_core(const float* __restrict__ Abase, int rowStride,
                                          const float* __restrict__ W,
                                          int jc0, int b, int tid,
                                          float* __restrict__ acc, float* __restrict__ lds)
{
#pragma unroll
  for (int c=0;c<COLS;c++) acc[c]=0.0f;
  constexpr int C4 = KCHUNK/4;
  for (int kb=0; kb<KDIM; kb+=KCHUNK) {
    __syncthreads();
    for (int i = tid; i < Bz*C4; i += 256) {
      int r  = i / C4;
      int c4 = i % C4;
      float4 v = *(const float4*)(Abase + (size_t)r*rowStride + kb + c4*4);
      *(float4*)(lds + r*LDA + c4*4) = v;
    }
    __syncthreads();
    const float* arow  = lds + b*LDA;
    const float* wbase = W + (size_t)jc0*KDIM + kb;
    for (int k=0;k<KCHUNK;k+=4) {
      float4 a = *(const float4*)(arow + k);
#pragma unroll
      for (int c=0;c<COLS;c++) {
        float4 w = *(const float4*)(wbase + (size_t)c*KDIM + k);
        acc[c] = fmaf(a.x,w.x,fmaf(a.y,w.y,fmaf(a.z,w.z,fmaf(a.w,w.w,acc[c]))));
      }
    }
  }
}

// ---- kP: pT[j][b] = ctx[b]·Wp[j] + bp[j] + bi[j] + (j<2H ? bh[j] : bc[j-2H])
__global__ __launch_bounds__(256)
void kP(const float* __restrict__ ctx, const float* __restrict__ Wp,
        const float* __restrict__ bp, const float* __restrict__ bh,
        const float* __restrict__ bc, const float* __restrict__ bi,
        float* __restrict__ pT)
{
  __shared__ float lds[Bz*LDA];
  int tid=threadIdx.x; int b=tid&63;
  int wv=__builtin_amdgcn_readfirstlane(tid>>6);
  int jc0 = blockIdx.x*16 + wv*4;
  float acc[4];
  gemm_core<4, Hz>(ctx, Hz, Wp, jc0, b, tid, acc, lds);
#pragma unroll
  for(int c=0;c<4;c++){
    int j=jc0+c;
    float v = acc[c] + bp[j] + bi[j] + (j < 2*Hz ? bh[j] : bc[j-2*Hz]);
    pT[(size_t)j*64 + b] = v;
  }
}

// ---- kI: hF quad-layout init + hB bf16 init. 64 blocks x 256 thr.
// hF quad layout: hF[((j>>2)*64 + b)*4 + (j&3)]
__global__ __launch_bounds__(256)
void kI(const float* __restrict__ h0, float* __restrict__ hF, unsigned short* __restrict__ hB)
{
  int b = blockIdx.x;
  int j = threadIdx.x*4;
  float4 v = *(const float4*)(h0 + (size_t)b*Hz + j);
  *(float4*)(hF + ((size_t)(j>>2)*64 + b)*4) = v;
  unsigned long long pk = (unsigned long long)pk2(v.x,v.y)
                        | ((unsigned long long)pk2(v.z,v.w) << 32);
  *(unsigned long long*)(hB + (size_t)b*Hz + j) = pk;
}

// ---- kAm: MFMA input GEMM. igT[t][j][b] = bf16( x[b,t]·Wi[j] + pT[j][b] )
__global__ __launch_bounds__(1024)
void kAm(const float* __restrict__ x, const float* __restrict__ Wi,
         const float* __restrict__ pT, unsigned short* __restrict__ igT)
{
  __shared__ unsigned short wiF[4*16*64*8];  // 64 KB
  __shared__ unsigned short xs[64*528];      // 66 KB
  __shared__ unsigned short igs[64*64];      // 8 KB
  const int tid = threadIdx.x;
  const int lane = tid & 63;
  const int w = __builtin_amdgcn_readfirstlane(tid >> 6);
  const int j0 = blockIdx.x * 64;
  const int t0 = blockIdx.y * 16;
  const int mt = w >> 2, nt = w & 3;
  const int bb = nt*16 + (lane & 15);
  const int q  = lane >> 4;
  const int jl = mt*16 + q*4;

  for (int idx = tid; idx < 4096; idx += 1024) {
    int mt2 = idx >> 10;
    int ks = (idx >> 6) & 15;
    int ln = idx & 63;
    int j = j0 + mt2*16 + (ln & 15);
    int k = ks*32 + (ln >> 4)*8;
    const float* s = Wi + (size_t)j*Dz + k;
    unsigned short* d = wiF + (size_t)idx*8;
#pragma unroll
    for (int qq=0;qq<8;qq++) d[qq] = f2b(s[qq]);
  }
  float pv[4];
#pragma unroll
  for (int r=0;r<4;r++) pv[r] = pT[(size_t)(j0+jl+r)*64 + bb];

  for (int it=0; it<16; it++) {
    int t = t0 + it;
    __syncthreads();
    for (int i = tid; i < 64*32; i += 1024) {
      int b = i >> 5, c = i & 31;
      const float* s = x + ((size_t)b*Tz + t)*Dz + c*16;
      unsigned* d = (unsigned*)(xs + (size_t)b*528 + c*16);
      float4 v0 = *(const float4*)(s);
      float4 v1 = *(const float4*)(s+4);
      float4 v2 = *(const float4*)(s+8);
      float4 v3 = *(const float4*)(s+12);
      d[0]=pk2(v0.x,v0.y); d[1]=pk2(v0.z,v0.w);
      d[2]=pk2(v1.x,v1.y); d[3]=pk2(v1.z,v1.w);
      d[4]=pk2(v2.x,v2.y); d[5]=pk2(v2.z,v2.w);
      d[6]=pk2(v3.x,v3.y); d[7]=pk2(v3.z,v3.w);
    }
    __syncthreads();
    f32x4 acc = {0.f,0.f,0.f,0.f};
    const unsigned short* bsrc = xs + (size_t)bb*528 + q*8;
#pragma unroll
    for (int ks=0; ks<16; ks++) {
      bf16x8 a = *(const bf16x8*)(wiF + ((size_t)(mt*16+ks)*64 + lane)*8);
      bf16x8 b = *(const bf16x8*)(bsrc + ks*32);
      acc = __builtin_amdgcn_mfma_f32_16x16x32_bf16(a, b, acc, 0, 0, 0);
    }
#pragma unroll
    for (int r=0;r<4;r++) igs[(size_t)(jl+r)*64 + bb] = f2b(acc[r] + pv[r]);
    __syncthreads();
    if (tid < 512) {
      int j = tid >> 3, seg = tid & 7;
      *(uint4*)(igT + ((size_t)t*G3 + j0 + j)*64 + seg*8) =
        *(const uint4*)(igs + (size_t)j*64 + seg*8);
    }
  }
}

// ---- krec: persistent MFMA recurrence, 64 blocks x 1024 threads.
// Identical data flow to the proven 7039us kernel (single-buffered hF/hB);
// only the grid-barrier implementation changed (single-hop all-to-all).
__global__ __launch_bounds__(1024)
void krec(const float* __restrict__ Wh, const float* __restrict__ Wc,
          const unsigned short* __restrict__ igT,
          float* __restrict__ hF, unsigned short* __restrict__ hB,
          unsigned short* __restrict__ rhB, float* __restrict__ iT,
          float* __restrict__ out, int* flags)
{
  __shared__ unsigned short whF[2*32*64*8];  // 64 KB
  __shared__ unsigned short wcF[32*64*8];    // 32 KB
  __shared__ float red[16*64*4];             // 16 KB
  const int tid = threadIdx.x;
  const int lane = tid & 63;
  const int w = __builtin_amdgcn_readfirstlane(tid >> 6);
  const int n = blockIdx.x;

  // fragment-swizzle weight slices (f32 -> bf16), one-time
  for (int idx = tid; idx < 4096; idx += 1024) {
    int mt = idx >> 11;
    int ks = (idx >> 6) & 31;
    int ln = idx & 63;
    int j = n*32 + mt*16 + (ln & 15);
    int k = ks*32 + (ln >> 4)*8;
    const float* s = Wh + (size_t)j*Hz + k;
    unsigned short* d = whF + (size_t)idx*8;
#pragma unroll
    for (int qq=0;qq<8;qq++) d[qq] = f2b(s[qq]);
  }
  for (int idx = tid; idx < 2048; idx += 1024) {
    int ks = (idx >> 6) & 31;
    int ln = idx & 63;
    int j = n*16 + (ln & 15);
    int k = ks*32 + (ln >> 4)*8;
    const float* s = Wc + (size_t)j*Hz + k;
    unsigned short* d = wcF + (size_t)idx*8;
#pragma unroll
    for (int qq=0;qq<8;qq++) d[qq] = f2b(s[qq]);
  }

  for (int t=0;t<Tz;t++) {
    const unsigned short* igt = igT + (size_t)t*G3*64;
    // ---------- phase 1: gates r,i ----------
    {
      int tp = w & 7, kh = w >> 3;        // 8 tiles x split-K-2
      int mt = tp >> 2, nt = tp & 3;
      int bb = nt*16 + (lane & 15);
      int q  = lane >> 4;
      int jg = n*32 + mt*16 + q*4;        // gate col in [0,2048)
      float igv[4], hv[4];
      if (w < 8) {
#pragma unroll
        for (int r=0;r<4;r++) igv[r] = b2f(igt[(size_t)(jg+r)*64 + bb]);
        if (n < 32) {
          const float* hp = hF + ((size_t)(jg>>2)*64 + bb)*4;
          float2 a01 = cldf2(hp), a23 = cldf2(hp+2);
          hv[0]=a01.x; hv[1]=a01.y; hv[2]=a23.x; hv[3]=a23.y;
        }
      }
      f32x4 acc = {0.f,0.f,0.f,0.f};
      const unsigned short* bsrc = hB + (size_t)bb*Hz + q*8;
      const unsigned short* asrc = whF + ((size_t)(mt*32 + kh*16)*64 + lane)*8;
#pragma unroll
      for (int ks=0; ks<16; ks++) {
        bf16x8 a = *(const bf16x8*)(asrc + (size_t)ks*64*8);
        bf16x8 b = cldb8(bsrc + (size_t)(kh*16+ks)*32);
        acc = __builtin_amdgcn_mfma_f32_16x16x32_bf16(a, b, acc, 0, 0, 0);
      }
      *(f32x4*)(red + ((size_t)w*64 + lane)*4) = acc;
      __syncthreads();
      if (w < 8) {
        f32x4 o  = *(const f32x4*)(red + ((size_t)w*64+lane)*4);
        f32x4 p2 = *(const f32x4*)(red + ((size_t)(w+8)*64+lane)*4);
        if (n < 32) {
          unsigned long long pk = 0;
#pragma unroll
          for (int r=0;r<4;r++) {
            float g = sigm(o[r] + p2[r] + igv[r]);
            pk |= (unsigned long long)f2b(g * hv[r]) << (16*r);
          }
          cst64(rhB + (size_t)bb*Hz + jg, pk);
        } else {
          float g0 = sigm(o[0] + p2[0] + igv[0]);
          float g1 = sigm(o[1] + p2[1] + igv[1]);
          float g2 = sigm(o[2] + p2[2] + igv[2]);
          float g3 = sigm(o[3] + p2[3] + igv[3]);
          float* ip = iT + ((size_t)((jg-1024)>>2)*64 + bb)*4;
          cstf2(ip, g0, g1); cstf2(ip+2, g2, g3);
        }
      }
    }
    gbar(flags, 2*t+1);
    // ---------- phase 2: n-gate + h update ----------
    {
      int nt = w & 3, kq = w >> 2;        // 4 tiles x split-K-4
      int bb = nt*16 + (lane & 15);
      int q  = lane >> 4;
      int jn = n*16 + q*4;                // col in [0,1024)
      float igv[4], hv[4], iv[4];
      if (w < 4) {
#pragma unroll
        for (int r=0;r<4;r++) igv[r] = b2f(igt[(size_t)(2048+jn+r)*64 + bb]);
        const float* hp = hF + ((size_t)(jn>>2)*64 + bb)*4;
        float2 a01 = cldf2(hp), a23 = cldf2(hp+2);
        hv[0]=a01.x; hv[1]=a01.y; hv[2]=a23.x; hv[3]=a23.y;
        const float* ip = iT + ((size_t)(jn>>2)*64 + bb)*4;
        float2 b01 = cldf2(ip), b23 = cldf2(ip+2);
        iv[0]=b01.x; iv[1]=b01.y; iv[2]=b23.x; iv[3]=b23.y;
      }
      f32x4 acc = {0.f,0.f,0.f,0.f};
      const unsigned short* bsrc = rhB + (size_t)bb*Hz + q*8;
#pragma unroll
      for (int ks=0; ks<8; ks++) {
        bf16x8 a = *(const bf16x8*)(wcF + ((size_t)(kq*8+ks)*64 + lane)*8);
        bf16x8 b = cldb8(bsrc + (size_t)(kq*8+ks)*32);
        acc = __builtin_amdgcn_mfma_f32_16x16x32_bf16(a, b, acc, 0, 0, 0);
      }
      *(f32x4*)(red + ((size_t)w*64 + lane)*4) = acc;
      __syncthreads();
      if (w < 4) {
        f32x4 s0 = *(const f32x4*)(red + ((size_t)w*64+lane)*4);
        f32x4 s1 = *(const f32x4*)(red + ((size_t)(w+4)*64+lane)*4);
        f32x4 s2 = *(const f32x4*)(red + ((size_t)(w+8)*64+lane)*4);
        f32x4 s3 = *(const f32x4*)(red + ((size_t)(w+12)*64+lane)*4);
        float hy4[4];
        unsigned long long pk = 0;
#pragma unroll
        for (int r=0;r<4;r++) {
          float g  = s0[r]+s1[r]+s2[r]+s3[r] + igv[r];
          float ng = tanhf(g);
          float hy = hv[r] + iv[r]*(ng - hv[r]);
          hy4[r] = hy;
          pk |= (unsigned long long)f2b(hy) << (16*r);
        }
        float* hp = hF + ((size_t)(jn>>2)*64 + bb)*4;
        cstf2(hp,   hy4[0], hy4[1]);
        cstf2(hp+2, hy4[2], hy4[3]);
        cst64(hB + (size_t)bb*Hz + jn, pk);
        float4 ov; ov.x=hy4[0]; ov.y=hy4[1]; ov.z=hy4[2]; ov.w=hy4[3];
        *(float4*)(out + ((size_t)bb*Tz + t)*Hz + jn) = ov;
      }
    }
    gbar(flags, 2*t+2);
  }
}

// ---- final hidden state: hN[b][j] = hF(quad)[j][b]
__global__ __launch_bounds__(256)
void ktr(const float* __restrict__ hF, float* __restrict__ hN)
{
  int b = blockIdx.x;
  int j = threadIdx.x*4;
  float4 v = *(const float4*)(hF + ((size_t)(j>>2)*64 + b)*4);
  *(float4*)(hN + (size_t)b*Hz + j) = v;
}

extern "C" void kernel_launch(void* const* d_in, const int* in_sizes, int n_in,
                              void* d_out, int out_size, void* d_ws, size_t ws_size,
                              hipStream_t stream)
{
  const float* x   = (const float*)d_in[0];
  const float* h0  = (const float*)d_in[1];
  const float* ctx = (const float*)d_in[2];
  const float* Wi  = (const float*)d_in[3];
  const float* bi  = (const float*)d_in[4];
  const float* Wh  = (const float*)d_in[5];
  const float* bh  = (const float*)d_in[6];
  const float* Wp  = (const float*)d_in[7];
  const float* bp  = (const float*)d_in[8];
  const float* Wc  = (const float*)d_in[9];
  const float* bc  = (const float*)d_in[10];
  float* out = (float*)d_out;

  char* wsp = (char*)d_ws;
  float* pT  = (float*)wsp; wsp += (size_t)G3*64*sizeof(float);       // 768 KB
  float* hF  = (float*)wsp; wsp += (size_t)Hz*64*sizeof(float);       // 256 KB
  float* iT  = (float*)wsp; wsp += (size_t)Hz*64*sizeof(float);       // 256 KB
  unsigned short* hB  = (unsigned short*)wsp; wsp += (size_t)Bz*Hz*2; // 128 KB
  unsigned short* rhB = (unsigned short*)wsp; wsp += (size_t)Bz*Hz*2; // 128 KB
  int* flags = (int*)wsp; wsp += 512;                                 // flags[64]
  unsigned short* igT = (unsigned short*)wsp;                         // 96 MB

  hipMemsetAsync(flags, 0, 512, stream);
  kP  <<<dim3(G3/16),   256,  0, stream>>>(ctx, Wp, bp, bh, bc, bi, pT);
  kI  <<<dim3(64),      256,  0, stream>>>(h0, hF, hB);
  kAm <<<dim3(48,16),   1024, 0, stream>>>(x, Wi, pT, igT);
  krec<<<dim3(NBK),     1024, 0, stream>>>(Wh, Wc, igT, hF, hB, rhB, iT, out, flags);
  ktr <<<dim3(64),      256,  0, stream>>>(hF, out + (size_t)Bz*Tz*Hz);
}

// Round 5
// 6977.871 us; speedup vs baseline: 1.0442x; 1.0442x over previous
//
#include <hip/hip_runtime.h>
#include <hip/hip_bf16.h>
#include <math.h>

#define Bz 64
#define Tz 256
#define Dz 512
#define Hz 1024
#define G3 3072
#define NBK 64      // blocks in persistent recurrence kernel

typedef short bf16x8 __attribute__((ext_vector_type(8)));
typedef float f32x4 __attribute__((ext_vector_type(4)));

__device__ __forceinline__ float sigm(float x){ return 1.0f/(1.0f+expf(-x)); }

__device__ __forceinline__ unsigned short f2b(float f){
  union{float f;unsigned u;}v; v.f=f;
  unsigned r = v.u + 0x7FFFu + ((v.u>>16)&1u);
  return (unsigned short)(r>>16);
}
__device__ __forceinline__ float b2f(unsigned short s){
  union{unsigned u;float f;}v; v.u = ((unsigned)s)<<16; return v.f;
}
__device__ __forceinline__ unsigned pk2(float a, float b){
  return (unsigned)f2b(a) | ((unsigned)f2b(b)<<16);
}

// ---- coherent (agent-scope, sc1; no-fence) access helpers ----
__device__ __forceinline__ unsigned long long cld64(const void* p){
  return __hip_atomic_load((const unsigned long long*)p, __ATOMIC_RELAXED, __HIP_MEMORY_SCOPE_AGENT);
}
__device__ __forceinline__ void cst64(void* p, unsigned long long v){
  __hip_atomic_store((unsigned long long*)p, v, __ATOMIC_RELAXED, __HIP_MEMORY_SCOPE_AGENT);
}
__device__ __forceinline__ float2 cldf2(const float* p){
  union { unsigned long long u; float2 f; } U; U.u = cld64(p); return U.f;
}
__device__ __forceinline__ void cstf2(float* p, float a, float b){
  union { unsigned long long u; float2 f; } U; U.f = make_float2(a,b); cst64(p, U.u);
}
__device__ __forceinline__ bf16x8 cldb8(const unsigned short* p){
  union { unsigned long long u[2]; bf16x8 v; } U;
  U.u[0] = cld64(p); U.u[1] = cld64(p+4);
  return U.v;
}
__device__ __forceinline__ int cld32(const int* p){
  return __hip_atomic_load(p, __ATOMIC_RELAXED, __HIP_MEMORY_SCOPE_AGENT);
}
__device__ __forceinline__ void cst32(int* p, int v){
  __hip_atomic_store(p, v, __ATOMIC_RELAXED, __HIP_MEMORY_SCOPE_AGENT);
}

// ---- fine-grained canary wait: one wave polls 64 per-block canaries,
// one per lane (4 cache lines). Producers publish via plain sc1 stores to
// distinct words (no RMW serialization — round-4 lesson).
__device__ __forceinline__ void waitcan(const int* can, int tgt){
  int l = threadIdx.x & 63;
  while (!__all(cld32(can + l) >= tgt))
    __builtin_amdgcn_s_sleep(1);
  asm volatile("" ::: "memory");
}

// ---------------- f32 skinny GEMM core (kP only, tiny) ----------------
#define KCHUNK 128
#define LDA 132
template<int COLS, int KDIM>
__device__ __forceinline__ void gemm_core(const float* __restrict__ Abase, int rowStride,
                                          const float* __restrict__ W,
                                          int jc0, int b, int tid,
                                          float* __restrict__ acc, float* __restrict__ lds)
{
#pragma unroll
  for (int c=0;c<COLS;c++) acc[c]=0.0f;
  constexpr int C4 = KCHUNK/4;
  for (int kb=0; kb<KDIM; kb+=KCHUNK) {
    __syncthreads();
    for (int i = tid; i < Bz*C4; i += 256) {
      int r  = i / C4;
      int c4 = i % C4;
      float4 v = *(const float4*)(Abase + (size_t)r*rowStride + kb + c4*4);
      *(float4*)(lds + r*LDA + c4*4) = v;
    }
    __syncthreads();
    const float* arow  = lds + b*LDA;
    const float* wbase = W + (size_t)jc0*KDIM + kb;
    for (int k=0;k<KCHUNK;k+=4) {
      float4 a = *(const float4*)(arow + k);
#pragma unroll
      for (int c=0;c<COLS;c++) {
        float4 w = *(const float4*)(wbase + (size_t)c*KDIM + k);
        acc[c] = fmaf(a.x,w.x,fmaf(a.y,w.y,fmaf(a.z,w.z,fmaf(a.w,w.w,acc[c]))));
      }
    }
  }
}

// ---- kP: pT[j][b] = ctx[b]·Wp[j] + bp[j] + bi[j] + (j<2H ? bh[j] : bc[j-2H])
__global__ __launch_bounds__(256)
void kP(const float* __restrict__ ctx, const float* __restrict__ Wp,
        const float* __restrict__ bp, const float* __restrict__ bh,
        const float* __restrict__ bc, const float* __restrict__ bi,
        float* __restrict__ pT)
{
  __shared__ float lds[Bz*LDA];
  int tid=threadIdx.x; int b=tid&63;
  int wv=__builtin_amdgcn_readfirstlane(tid>>6);
  int jc0 = blockIdx.x*16 + wv*4;
  float acc[4];
  gemm_core<4, Hz>(ctx, Hz, Wp, jc0, b, tid, acc, lds);
#pragma unroll
  for(int c=0;c<4;c++){
    int j=jc0+c;
    float v = acc[c] + bp[j] + bi[j] + (j < 2*Hz ? bh[j] : bc[j-2*Hz]);
    pT[(size_t)j*64 + b] = v;
  }
}

// ---- kI: hF quad-layout init + hB bf16 init (parity-0 buffers). 64 blocks x 256 thr.
// hF quad layout: hF[((j>>2)*64 + b)*4 + (j&3)]
__global__ __launch_bounds__(256)
void kI(const float* __restrict__ h0, float* __restrict__ hF, unsigned short* __restrict__ hB)
{
  int b = blockIdx.x;
  int j = threadIdx.x*4;
  float4 v = *(const float4*)(h0 + (size_t)b*Hz + j);
  *(float4*)(hF + ((size_t)(j>>2)*64 + b)*4) = v;
  unsigned long long pk = (unsigned long long)pk2(v.x,v.y)
                        | ((unsigned long long)pk2(v.z,v.w) << 32);
  *(unsigned long long*)(hB + (size_t)b*Hz + j) = pk;
}

// ---- kAm: MFMA input GEMM. igT[t][j][b] = bf16( x[b,t]·Wi[j] + pT[j][b] )
__global__ __launch_bounds__(1024)
void kAm(const float* __restrict__ x, const float* __restrict__ Wi,
         const float* __restrict__ pT, unsigned short* __restrict__ igT)
{
  __shared__ unsigned short wiF[4*16*64*8];  // 64 KB
  __shared__ unsigned short xs[64*528];      // 66 KB
  __shared__ unsigned short igs[64*64];      // 8 KB
  const int tid = threadIdx.x;
  const int lane = tid & 63;
  const int w = __builtin_amdgcn_readfirstlane(tid >> 6);
  const int j0 = blockIdx.x * 64;
  const int t0 = blockIdx.y * 16;
  const int mt = w >> 2, nt = w & 3;
  const int bb = nt*16 + (lane & 15);
  const int q  = lane >> 4;
  const int jl = mt*16 + q*4;

  for (int idx = tid; idx < 4096; idx += 1024) {
    int mt2 = idx >> 10;
    int ks = (idx >> 6) & 15;
    int ln = idx & 63;
    int j = j0 + mt2*16 + (ln & 15);
    int k = ks*32 + (ln >> 4)*8;
    const float* s = Wi + (size_t)j*Dz + k;
    unsigned short* d = wiF + (size_t)idx*8;
#pragma unroll
    for (int qq=0;qq<8;qq++) d[qq] = f2b(s[qq]);
  }
  float pv[4];
#pragma unroll
  for (int r=0;r<4;r++) pv[r] = pT[(size_t)(j0+jl+r)*64 + bb];

  for (int it=0; it<16; it++) {
    int t = t0 + it;
    __syncthreads();
    for (int i = tid; i < 64*32; i += 1024) {
      int b = i >> 5, c = i & 31;
      const float* s = x + ((size_t)b*Tz + t)*Dz + c*16;
      unsigned* d = (unsigned*)(xs + (size_t)b*528 + c*16);
      float4 v0 = *(const float4*)(s);
      float4 v1 = *(const float4*)(s+4);
      float4 v2 = *(const float4*)(s+8);
      float4 v3 = *(const float4*)(s+12);
      d[0]=pk2(v0.x,v0.y); d[1]=pk2(v0.z,v0.w);
      d[2]=pk2(v1.x,v1.y); d[3]=pk2(v1.z,v1.w);
      d[4]=pk2(v2.x,v2.y); d[5]=pk2(v2.z,v2.w);
      d[6]=pk2(v3.x,v3.y); d[7]=pk2(v3.z,v3.w);
    }
    __syncthreads();
    f32x4 acc = {0.f,0.f,0.f,0.f};
    const unsigned short* bsrc = xs + (size_t)bb*528 + q*8;
#pragma unroll
    for (int ks=0; ks<16; ks++) {
      bf16x8 a = *(const bf16x8*)(wiF + ((size_t)(mt*16+ks)*64 + lane)*8);
      bf16x8 b = *(const bf16x8*)(bsrc + ks*32);
      acc = __builtin_amdgcn_mfma_f32_16x16x32_bf16(a, b, acc, 0, 0, 0);
    }
#pragma unroll
    for (int r=0;r<4;r++) igs[(size_t)(jl+r)*64 + bb] = f2b(acc[r] + pv[r]);
    __syncthreads();
    if (tid < 512) {
      int j = tid >> 3, seg = tid & 7;
      *(uint4*)(igT + ((size_t)t*G3 + j0 + j)*64 + seg*8) =
        *(const uint4*)(igs + (size_t)j*64 + seg*8);
    }
  }
}

// ---- krec: persistent MFMA recurrence, 64 blocks x 1024 threads.
// Fine-grained canary sync (no grid barrier):
//   canP[n] = t+1  published by block n after phase 1 of step t (rhB / iT ready)
//   canH[n] = t+1  published by block n after phase 2 of step t (h_{t+1} ready)
// Phase 1 waits canH >= t (needs h_t); phase 2 waits canP >= t+1 (needs rhB_t, iT_t).
// hB/hF double-buffered by t-parity (WAR safety); rhB/iT single-buffered
// (overwrite at step t+1 ordered after all step-t consumers via canH/canP chains).
// Wait-graph is a DAG grounded by the stream-ordered memset -> no deadlock.
__global__ __launch_bounds__(1024)
void krec(const float* __restrict__ Wh, const float* __restrict__ Wc,
          const unsigned short* __restrict__ igT,
          float* __restrict__ hF0, float* __restrict__ hF1,
          unsigned short* __restrict__ hB0, unsigned short* __restrict__ hB1,
          unsigned short* __restrict__ rhB, float* __restrict__ iT,
          float* __restrict__ out, int* canP, int* canH)
{
  __shared__ unsigned short whF[2*32*64*8];  // 64 KB
  __shared__ unsigned short wcF[32*64*8];    // 32 KB
  __shared__ float red[16*64*4];             // 16 KB
  const int tid = threadIdx.x;
  const int lane = tid & 63;
  const int w = __builtin_amdgcn_readfirstlane(tid >> 6);
  const int n = blockIdx.x;

  // fragment-swizzle weight slices (f32 -> bf16), one-time
  for (int idx = tid; idx < 4096; idx += 1024) {
    int mt = idx >> 11;
    int ks = (idx >> 6) & 31;
    int ln = idx & 63;
    int j = n*32 + mt*16 + (ln & 15);
    int k = ks*32 + (ln >> 4)*8;
    const float* s = Wh + (size_t)j*Hz + k;
    unsigned short* d = whF + (size_t)idx*8;
#pragma unroll
    for (int qq=0;qq<8;qq++) d[qq] = f2b(s[qq]);
  }
  for (int idx = tid; idx < 2048; idx += 1024) {
    int ks = (idx >> 6) & 31;
    int ln = idx & 63;
    int j = n*16 + (ln & 15);
    int k = ks*32 + (ln >> 4)*8;
    const float* s = Wc + (size_t)j*Hz + k;
    unsigned short* d = wcF + (size_t)idx*8;
#pragma unroll
    for (int qq=0;qq<8;qq++) d[qq] = f2b(s[qq]);
  }

  for (int t=0;t<Tz;t++) {
    const unsigned short* igt = igT + (size_t)t*G3*64;
    const unsigned short* hBr = (t&1) ? hB1 : hB0;
    unsigned short*       hBw = (t&1) ? hB0 : hB1;
    const float*          hFr = (t&1) ? hF1 : hF0;
    float*                hFw = (t&1) ? hF0 : hF1;
    // ---------- phase 1: gates r,i ----------
    {
      int tp = w & 7, kh = w >> 3;        // 8 tiles x split-K-2
      int mt = tp >> 2, nt = tp & 3;
      int bb = nt*16 + (lane & 15);
      int q  = lane >> 4;
      int jg = n*32 + mt*16 + q*4;        // gate col in [0,2048)
      float igv[4], hv[4];
      if (w < 8) {                        // igT prefetch: independent of sync
#pragma unroll
        for (int r=0;r<4;r++) igv[r] = b2f(igt[(size_t)(jg+r)*64 + bb]);
      }
      if (w == 0) waitcan(canH, t);       // h_t ready (all 64 producers)
      __syncthreads();
      if (w < 8 && n < 32) {
        const float* hp = hFr + ((size_t)(jg>>2)*64 + bb)*4;
        float2 a01 = cldf2(hp), a23 = cldf2(hp+2);
        hv[0]=a01.x; hv[1]=a01.y; hv[2]=a23.x; hv[3]=a23.y;
      }
      f32x4 acc = {0.f,0.f,0.f,0.f};
      const unsigned short* bsrc = hBr + (size_t)bb*Hz + q*8;
      const unsigned short* asrc = whF + ((size_t)(mt*32 + kh*16)*64 + lane)*8;
#pragma unroll
      for (int ks=0; ks<16; ks++) {
        bf16x8 a = *(const bf16x8*)(asrc + (size_t)ks*64*8);
        bf16x8 b = cldb8(bsrc + (size_t)(kh*16+ks)*32);
        acc = __builtin_amdgcn_mfma_f32_16x16x32_bf16(a, b, acc, 0, 0, 0);
      }
      *(f32x4*)(red + ((size_t)w*64 + lane)*4) = acc;
      __syncthreads();
      if (w < 8) {
        f32x4 o  = *(const f32x4*)(red + ((size_t)w*64+lane)*4);
        f32x4 p2 = *(const f32x4*)(red + ((size_t)(w+8)*64+lane)*4);
        if (n < 32) {
          unsigned long long pk = 0;
#pragma unroll
          for (int r=0;r<4;r++) {
            float g = sigm(o[r] + p2[r] + igv[r]);
            pk |= (unsigned long long)f2b(g * hv[r]) << (16*r);
          }
          cst64(rhB + (size_t)bb*Hz + jg, pk);
        } else {
          float g0 = sigm(o[0] + p2[0] + igv[0]);
          float g1 = sigm(o[1] + p2[1] + igv[1]);
          float g2 = sigm(o[2] + p2[2] + igv[2]);
          float g3 = sigm(o[3] + p2[3] + igv[3]);
          float* ip = iT + ((size_t)((jg-1024)>>2)*64 + bb)*4;
          cstf2(ip, g0, g1); cstf2(ip+2, g2, g3);
        }
      }
      __syncthreads();                    // drains writer waves' vmcnt -> stores agent-visible
      if (tid == 0) cst32(canP + n, t+1); // publish: rhB/iT slice of step t ready
    }
    // ---------- phase 2: n-gate + h update ----------
    {
      int nt = w & 3, kq = w >> 2;        // 4 tiles x split-K-4
      int bb = nt*16 + (lane & 15);
      int q  = lane >> 4;
      int jn = n*16 + q*4;                // col in [0,1024)
      float igv[4], hv[4], iv[4];
      if (w < 4) {                        // igT prefetch: independent of sync
#pragma unroll
        for (int r=0;r<4;r++) igv[r] = b2f(igt[(size_t)(2048+jn+r)*64 + bb]);
      }
      if (w == 0) waitcan(canP, t+1);     // rhB_t + iT_t ready (all 64 producers)
      __syncthreads();
      if (w < 4) {
        const float* hp = hFr + ((size_t)(jn>>2)*64 + bb)*4;
        float2 a01 = cldf2(hp), a23 = cldf2(hp+2);
        hv[0]=a01.x; hv[1]=a01.y; hv[2]=a23.x; hv[3]=a23.y;
        const float* ip = iT + ((size_t)(jn>>2)*64 + bb)*4;
        float2 b01 = cldf2(ip), b23 = cldf2(ip+2);
        iv[0]=b01.x; iv[1]=b01.y; iv[2]=b23.x; iv[3]=b23.y;
      }
      f32x4 acc = {0.f,0.f,0.f,0.f};
      const unsigned short* bsrc = rhB + (size_t)bb*Hz + q*8;
#pragma unroll
      for (int ks=0; ks<8; ks++) {
        bf16x8 a = *(const bf16x8*)(wcF + ((size_t)(kq*8+ks)*64 + lane)*8);
        bf16x8 b = cldb8(bsrc + (size_t)(kq*8+ks)*32);
        acc = __builtin_amdgcn_mfma_f32_16x16x32_bf16(a, b, acc, 0, 0, 0);
      }
      *(f32x4*)(red + ((size_t)w*64 + lane)*4) = acc;
      __syncthreads();
      if (w < 4) {
        f32x4 s0 = *(const f32x4*)(red + ((size_t)w*64+lane)*4);
        f32x4 s1 = *(const f32x4*)(red + ((size_t)(w+4)*64+lane)*4);
        f32x4 s2 = *(const f32x4*)(red + ((size_t)(w+8)*64+lane)*4);
        f32x4 s3 = *(const f32x4*)(red + ((size_t)(w+12)*64+lane)*4);
        float hy4[4];
        unsigned long long pk = 0;
#pragma unroll
        for (int r=0;r<4;r++) {
          float g  = s0[r]+s1[r]+s2[r]+s3[r] + igv[r];
          float ng = tanhf(g);
          float hy = hv[r] + iv[r]*(ng - hv[r]);
          hy4[r] = hy;
          pk |= (unsigned long long)f2b(hy) << (16*r);
        }
        float* hp = hFw + ((size_t)(jn>>2)*64 + bb)*4;
        cstf2(hp,   hy4[0], hy4[1]);
        cstf2(hp+2, hy4[2], hy4[3]);
        cst64(hBw + (size_t)bb*Hz + jn, pk);
        float4 ov; ov.x=hy4[0]; ov.y=hy4[1]; ov.z=hy4[2]; ov.w=hy4[3];
        *(float4*)(out + ((size_t)bb*Tz + t)*Hz + jn) = ov;
      }
      __syncthreads();                    // drains writer waves' vmcnt -> stores agent-visible
      if (tid == 0) cst32(canH + n, t+1); // publish: h_{t+1} slice ready
    }
  }
}

// ---- final hidden state: hN[b][j] = hF(quad)[j][b]
__global__ __launch_bounds__(256)
void ktr(const float* __restrict__ hF, float* __restrict__ hN)
{
  int b = blockIdx.x;
  int j = threadIdx.x*4;
  float4 v = *(const float4*)(hF + ((size_t)(j>>2)*64 + b)*4);
  *(float4*)(hN + (size_t)b*Hz + j) = v;
}

extern "C" void kernel_launch(void* const* d_in, const int* in_sizes, int n_in,
                              void* d_out, int out_size, void* d_ws, size_t ws_size,
                              hipStream_t stream)
{
  const float* x   = (const float*)d_in[0];
  const float* h0  = (const float*)d_in[1];
  const float* ctx = (const float*)d_in[2];
  const float* Wi  = (const float*)d_in[3];
  const float* bi  = (const float*)d_in[4];
  const float* Wh  = (const float*)d_in[5];
  const float* bh  = (const float*)d_in[6];
  const float* Wp  = (const float*)d_in[7];
  const float* bp  = (const float*)d_in[8];
  const float* Wc  = (const float*)d_in[9];
  const float* bc  = (const float*)d_in[10];
  float* out = (float*)d_out;

  char* wsp = (char*)d_ws;
  float* pT  = (float*)wsp; wsp += (size_t)G3*64*sizeof(float);        // 768 KB
  float* hF0 = (float*)wsp; wsp += (size_t)Hz*64*sizeof(float);        // 256 KB
  float* hF1 = (float*)wsp; wsp += (size_t)Hz*64*sizeof(float);        // 256 KB
  float* iT  = (float*)wsp; wsp += (size_t)Hz*64*sizeof(float);        // 256 KB
  unsigned short* hB0 = (unsigned short*)wsp; wsp += (size_t)Bz*Hz*2;  // 128 KB
  unsigned short* hB1 = (unsigned short*)wsp; wsp += (size_t)Bz*Hz*2;  // 128 KB
  unsigned short* rhB = (unsigned short*)wsp; wsp += (size_t)Bz*Hz*2;  // 128 KB
  int* canP = (int*)wsp; wsp += 512;                                   // canP[64] + canH[64]
  int* canH = canP + 64;
  unsigned short* igT = (unsigned short*)wsp;                          // 96 MB

  hipMemsetAsync(canP, 0, 512, stream);
  kP  <<<dim3(G3/16),   256,  0, stream>>>(ctx, Wp, bp, bh, bc, bi, pT);
  kI  <<<dim3(64),      256,  0, stream>>>(h0, hF0, hB0);
  kAm <<<dim3(48,16),   1024, 0, stream>>>(x, Wi, pT, igT);
  krec<<<dim3(NBK),     1024, 0, stream>>>(Wh, Wc, igT, hF0, hF1, hB0, hB1, rhB, iT, out, canP, canH);
  ktr <<<dim3(64),      256,  0, stream>>>(hF0, out + (size_t)Bz*Tz*Hz);
}

// Round 6
// 5608.347 us; speedup vs baseline: 1.2992x; 1.2442x over previous
//
#include <hip/hip_runtime.h>
#include <hip/hip_bf16.h>
#include <math.h>

#define Bz 64
#define Tz 256
#define Dz 512
#define Hz 1024
#define G3 3072
#define NBK 64      // blocks in persistent recurrence kernel

typedef short bf16x8 __attribute__((ext_vector_type(8)));
typedef float f32x4 __attribute__((ext_vector_type(4)));

__device__ __forceinline__ float sigm(float x){ return 1.0f/(1.0f+expf(-x)); }

__device__ __forceinline__ unsigned short f2b(float f){
  union{float f;unsigned u;}v; v.f=f;
  unsigned r = v.u + 0x7FFFu + ((v.u>>16)&1u);
  return (unsigned short)(r>>16);
}
__device__ __forceinline__ float b2f(unsigned short s){
  union{unsigned u;float f;}v; v.u = ((unsigned)s)<<16; return v.f;
}
__device__ __forceinline__ unsigned pk2(float a, float b){
  return (unsigned)f2b(a) | ((unsigned)f2b(b)<<16);
}

// ---- canary flag ops (agent scope). Data itself moves via PLAIN cached
// accesses; visibility is via release-store (bulk L2 writeback) + acquire
// (bulk L1/L2 invalidate) around the flags — round-5 lesson: per-element
// sc1 atomic data paths (no coalescing, no caching) were the bottleneck.
__device__ __forceinline__ int cld32(const int* p){
  return __hip_atomic_load(p, __ATOMIC_RELAXED, __HIP_MEMORY_SCOPE_AGENT);
}
__device__ __forceinline__ void pubrel(int* p, int v){
  __hip_atomic_store(p, v, __ATOMIC_RELEASE, __HIP_MEMORY_SCOPE_AGENT);
}
// one wave polls 64 per-block canaries (relaxed), then one acquire load
// (emits L1/L2 invalidate) BEFORE the caller's __syncthreads releases the
// consuming waves -> one inv covers the whole block's subsequent loads.
__device__ __forceinline__ void waitcan_acq(const int* can, int tgt){
  int l = threadIdx.x & 63;
  while (!__all(cld32(can + l) >= tgt))
    __builtin_amdgcn_s_sleep(1);
  __hip_atomic_load(can + l, __ATOMIC_ACQUIRE, __HIP_MEMORY_SCOPE_AGENT);
  asm volatile("" ::: "memory");
}

// ---------------- f32 skinny GEMM core (kP only, tiny) ----------------
#define KCHUNK 128
#define LDA 132
template<int COLS, int KDIM>
__device__ __forceinline__ void gemm_core(const float* __restrict__ Abase, int rowStride,
                                          const float* __restrict__ W,
                                          int jc0, int b, int tid,
                                          float* __restrict__ acc, float* __restrict__ lds)
{
#pragma unroll
  for (int c=0;c<COLS;c++) acc[c]=0.0f;
  constexpr int C4 = KCHUNK/4;
  for (int kb=0; kb<KDIM; kb+=KCHUNK) {
    __syncthreads();
    for (int i = tid; i < Bz*C4; i += 256) {
      int r  = i / C4;
      int c4 = i % C4;
      float4 v = *(const float4*)(Abase + (size_t)r*rowStride + kb + c4*4);
      *(float4*)(lds + r*LDA + c4*4) = v;
    }
    __syncthreads();
    const float* arow  = lds + b*LDA;
    const float* wbase = W + (size_t)jc0*KDIM + kb;
    for (int k=0;k<KCHUNK;k+=4) {
      float4 a = *(const float4*)(arow + k);
#pragma unroll
      for (int c=0;c<COLS;c++) {
        float4 w = *(const float4*)(wbase + (size_t)c*KDIM + k);
        acc[c] = fmaf(a.x,w.x,fmaf(a.y,w.y,fmaf(a.z,w.z,fmaf(a.w,w.w,acc[c]))));
      }
    }
  }
}

// ---- kP: pT[j][b] = ctx[b]·Wp[j] + bp[j] + bi[j] + (j<2H ? bh[j] : bc[j-2H])
__global__ __launch_bounds__(256)
void kP(const float* __restrict__ ctx, const float* __restrict__ Wp,
        const float* __restrict__ bp, const float* __restrict__ bh,
        const float* __restrict__ bc, const float* __restrict__ bi,
        float* __restrict__ pT)
{
  __shared__ float lds[Bz*LDA];
  int tid=threadIdx.x; int b=tid&63;
  int wv=__builtin_amdgcn_readfirstlane(tid>>6);
  int jc0 = blockIdx.x*16 + wv*4;
  float acc[4];
  gemm_core<4, Hz>(ctx, Hz, Wp, jc0, b, tid, acc, lds);
#pragma unroll
  for(int c=0;c<4;c++){
    int j=jc0+c;
    float v = acc[c] + bp[j] + bi[j] + (j < 2*Hz ? bh[j] : bc[j-2*Hz]);
    pT[(size_t)j*64 + b] = v;
  }
}

// ---- kI: hF quad-layout init + hB bf16 init (parity-0 buffers). 64 blocks x 256 thr.
// hF quad layout: hF[((j>>2)*64 + b)*4 + (j&3)]
__global__ __launch_bounds__(256)
void kI(const float* __restrict__ h0, float* __restrict__ hF, unsigned short* __restrict__ hB)
{
  int b = blockIdx.x;
  int j = threadIdx.x*4;
  float4 v = *(const float4*)(h0 + (size_t)b*Hz + j);
  *(float4*)(hF + ((size_t)(j>>2)*64 + b)*4) = v;
  unsigned long long pk = (unsigned long long)pk2(v.x,v.y)
                        | ((unsigned long long)pk2(v.z,v.w) << 32);
  *(unsigned long long*)(hB + (size_t)b*Hz + j) = pk;
}

// ---- kAm: MFMA input GEMM. igT[t][j][b] = bf16( x[b,t]·Wi[j] + pT[j][b] )
__global__ __launch_bounds__(1024)
void kAm(const float* __restrict__ x, const float* __restrict__ Wi,
         const float* __restrict__ pT, unsigned short* __restrict__ igT)
{
  __shared__ unsigned short wiF[4*16*64*8];  // 64 KB
  __shared__ unsigned short xs[64*528];      // 66 KB
  __shared__ unsigned short igs[64*64];      // 8 KB
  const int tid = threadIdx.x;
  const int lane = tid & 63;
  const int w = __builtin_amdgcn_readfirstlane(tid >> 6);
  const int j0 = blockIdx.x * 64;
  const int t0 = blockIdx.y * 16;
  const int mt = w >> 2, nt = w & 3;
  const int bb = nt*16 + (lane & 15);
  const int q  = lane >> 4;
  const int jl = mt*16 + q*4;

  for (int idx = tid; idx < 4096; idx += 1024) {
    int mt2 = idx >> 10;
    int ks = (idx >> 6) & 15;
    int ln = idx & 63;
    int j = j0 + mt2*16 + (ln & 15);
    int k = ks*32 + (ln >> 4)*8;
    const float* s = Wi + (size_t)j*Dz + k;
    unsigned short* d = wiF + (size_t)idx*8;
#pragma unroll
    for (int qq=0;qq<8;qq++) d[qq] = f2b(s[qq]);
  }
  float pv[4];
#pragma unroll
  for (int r=0;r<4;r++) pv[r] = pT[(size_t)(j0+jl+r)*64 + bb];

  for (int it=0; it<16; it++) {
    int t = t0 + it;
    __syncthreads();
    for (int i = tid; i < 64*32; i += 1024) {
      int b = i >> 5, c = i & 31;
      const float* s = x + ((size_t)b*Tz + t)*Dz + c*16;
      unsigned* d = (unsigned*)(xs + (size_t)b*528 + c*16);
      float4 v0 = *(const float4*)(s);
      float4 v1 = *(const float4*)(s+4);
      float4 v2 = *(const float4*)(s+8);
      float4 v3 = *(const float4*)(s+12);
      d[0]=pk2(v0.x,v0.y); d[1]=pk2(v0.z,v0.w);
      d[2]=pk2(v1.x,v1.y); d[3]=pk2(v1.z,v1.w);
      d[4]=pk2(v2.x,v2.y); d[5]=pk2(v2.z,v2.w);
      d[6]=pk2(v3.x,v3.y); d[7]=pk2(v3.z,v3.w);
    }
    __syncthreads();
    f32x4 acc = {0.f,0.f,0.f,0.f};
    const unsigned short* bsrc = xs + (size_t)bb*528 + q*8;
#pragma unroll
    for (int ks=0; ks<16; ks++) {
      bf16x8 a = *(const bf16x8*)(wiF + ((size_t)(mt*16+ks)*64 + lane)*8);
      bf16x8 b = *(const bf16x8*)(bsrc + ks*32);
      acc = __builtin_amdgcn_mfma_f32_16x16x32_bf16(a, b, acc, 0, 0, 0);
    }
#pragma unroll
    for (int r=0;r<4;r++) igs[(size_t)(jl+r)*64 + bb] = f2b(acc[r] + pv[r]);
    __syncthreads();
    if (tid < 512) {
      int j = tid >> 3, seg = tid & 7;
      *(uint4*)(igT + ((size_t)t*G3 + j0 + j)*64 + seg*8) =
        *(const uint4*)(igs + (size_t)j*64 + seg*8);
    }
  }
}

// ---- krec: persistent MFMA recurrence, 64 blocks x 1024 threads.
// Canary sync (round-5 protocol) + release/acquire data visibility:
//   producer: plain cached stores -> __syncthreads (vmcnt drain, stores in L2)
//             -> tid0 RELEASE canary store (bulk L2 writeback + flag)
//   consumer: wave0 relaxed poll -> ACQUIRE load (bulk L1/L2 invalidate)
//             -> __syncthreads -> plain cached loads (coalesced, line-granular)
// canP[n]=t+1 after phase1@t (rhB/iT ready); canH[n]=t+1 after phase2@t (h_{t+1}).
// Phase1@t waits canH>=t; phase2@t waits canP>=t+1. hF/hB parity double-buffered;
// rhB/iT single-buffered (WAR via the canH/canP chain). DAG grounded by memset.
__global__ __launch_bounds__(1024)
void krec(const float* __restrict__ Wh, const float* __restrict__ Wc,
          const unsigned short* __restrict__ igT,
          float* __restrict__ hF0, float* __restrict__ hF1,
          unsigned short* __restrict__ hB0, unsigned short* __restrict__ hB1,
          unsigned short* __restrict__ rhB, float* __restrict__ iT,
          float* __restrict__ out, int* canP, int* canH)
{
  __shared__ unsigned short whF[2*32*64*8];  // 64 KB
  __shared__ unsigned short wcF[32*64*8];    // 32 KB
  __shared__ float red[16*64*4];             // 16 KB
  const int tid = threadIdx.x;
  const int lane = tid & 63;
  const int w = __builtin_amdgcn_readfirstlane(tid >> 6);
  const int n = blockIdx.x;

  // fragment-swizzle weight slices (f32 -> bf16), one-time
  for (int idx = tid; idx < 4096; idx += 1024) {
    int mt = idx >> 11;
    int ks = (idx >> 6) & 31;
    int ln = idx & 63;
    int j = n*32 + mt*16 + (ln & 15);
    int k = ks*32 + (ln >> 4)*8;
    const float* s = Wh + (size_t)j*Hz + k;
    unsigned short* d = whF + (size_t)idx*8;
#pragma unroll
    for (int qq=0;qq<8;qq++) d[qq] = f2b(s[qq]);
  }
  for (int idx = tid; idx < 2048; idx += 1024) {
    int ks = (idx >> 6) & 31;
    int ln = idx & 63;
    int j = n*16 + (ln & 15);
    int k = ks*32 + (ln >> 4)*8;
    const float* s = Wc + (size_t)j*Hz + k;
    unsigned short* d = wcF + (size_t)idx*8;
#pragma unroll
    for (int qq=0;qq<8;qq++) d[qq] = f2b(s[qq]);
  }

  for (int t=0;t<Tz;t++) {
    const unsigned short* igt = igT + (size_t)t*G3*64;
    const unsigned short* hBr = (t&1) ? hB1 : hB0;
    unsigned short*       hBw = (t&1) ? hB0 : hB1;
    const float*          hFr = (t&1) ? hF1 : hF0;
    float*                hFw = (t&1) ? hF0 : hF1;
    // ---------- phase 1: gates r,i ----------
    {
      int tp = w & 7, kh = w >> 3;        // 8 tiles x split-K-2
      int mt = tp >> 2, nt = tp & 3;
      int bb = nt*16 + (lane & 15);
      int q  = lane >> 4;
      int jg = n*32 + mt*16 + q*4;        // gate col in [0,2048)
      float igv[4], hv[4];
      if (w < 8) {                        // igT prefetch: written pre-krec, any cached copy valid
#pragma unroll
        for (int r=0;r<4;r++) igv[r] = b2f(igt[(size_t)(jg+r)*64 + bb]);
      }
      if (w == 0) waitcan_acq(canH, t);   // h_t ready; acquire-inv before barrier release
      __syncthreads();
      if (w < 8 && n < 32) {
        f32x4 a = *(const f32x4*)(hFr + ((size_t)(jg>>2)*64 + bb)*4);
        hv[0]=a[0]; hv[1]=a[1]; hv[2]=a[2]; hv[3]=a[3];
      }
      f32x4 acc = {0.f,0.f,0.f,0.f};
      const unsigned short* bsrc = hBr + (size_t)bb*Hz + q*8;
      const unsigned short* asrc = whF + ((size_t)(mt*32 + kh*16)*64 + lane)*8;
#pragma unroll
      for (int ks=0; ks<16; ks++) {
        bf16x8 a = *(const bf16x8*)(asrc + (size_t)ks*64*8);
        bf16x8 b = *(const bf16x8*)(bsrc + (size_t)(kh*16+ks)*32);
        acc = __builtin_amdgcn_mfma_f32_16x16x32_bf16(a, b, acc, 0, 0, 0);
      }
      *(f32x4*)(red + ((size_t)w*64 + lane)*4) = acc;
      __syncthreads();
      if (w < 8) {
        f32x4 o  = *(const f32x4*)(red + ((size_t)w*64+lane)*4);
        f32x4 p2 = *(const f32x4*)(red + ((size_t)(w+8)*64+lane)*4);
        if (n < 32) {
          unsigned long long pk = 0;
#pragma unroll
          for (int r=0;r<4;r++) {
            float g = sigm(o[r] + p2[r] + igv[r]);
            pk |= (unsigned long long)f2b(g * hv[r]) << (16*r);
          }
          *(unsigned long long*)(rhB + (size_t)bb*Hz + jg) = pk;
        } else {
          f32x4 iv4;
          iv4[0] = sigm(o[0] + p2[0] + igv[0]);
          iv4[1] = sigm(o[1] + p2[1] + igv[1]);
          iv4[2] = sigm(o[2] + p2[2] + igv[2]);
          iv4[3] = sigm(o[3] + p2[3] + igv[3]);
          *(f32x4*)(iT + ((size_t)((jg-1024)>>2)*64 + bb)*4) = iv4;
        }
      }
      __syncthreads();                    // vmcnt drained -> stores in L2
      if (tid == 0) pubrel(canP + n, t+1);// release: wbl2 + flag (rhB/iT@t visible)
    }
    // ---------- phase 2: n-gate + h update ----------
    {
      int nt = w & 3, kq = w >> 2;        // 4 tiles x split-K-4
      int bb = nt*16 + (lane & 15);
      int q  = lane >> 4;
      int jn = n*16 + q*4;                // col in [0,1024)
      float igv[4], hv[4], iv[4];
      if (w < 4) {                        // igT prefetch: safe pre-acquire (stale-proof)
#pragma unroll
        for (int r=0;r<4;r++) igv[r] = b2f(igt[(size_t)(2048+jn+r)*64 + bb]);
      }
      if (w == 0) waitcan_acq(canP, t+1); // rhB_t + iT_t ready; acquire-inv
      __syncthreads();
      if (w < 4) {
        f32x4 a = *(const f32x4*)(hFr + ((size_t)(jn>>2)*64 + bb)*4);
        hv[0]=a[0]; hv[1]=a[1]; hv[2]=a[2]; hv[3]=a[3];
        f32x4 b = *(const f32x4*)(iT + ((size_t)(jn>>2)*64 + bb)*4);
        iv[0]=b[0]; iv[1]=b[1]; iv[2]=b[2]; iv[3]=b[3];
      }
      f32x4 acc = {0.f,0.f,0.f,0.f};
      const unsigned short* bsrc = rhB + (size_t)bb*Hz + q*8;
#pragma unroll
      for (int ks=0; ks<8; ks++) {
        bf16x8 a = *(const bf16x8*)(wcF + ((size_t)(kq*8+ks)*64 + lane)*8);
        bf16x8 b = *(const bf16x8*)(bsrc + (size_t)(kq*8+ks)*32);
        acc = __builtin_amdgcn_mfma_f32_16x16x32_bf16(a, b, acc, 0, 0, 0);
      }
      *(f32x4*)(red + ((size_t)w*64 + lane)*4) = acc;
      __syncthreads();
      if (w < 4) {
        f32x4 s0 = *(const f32x4*)(red + ((size_t)w*64+lane)*4);
        f32x4 s1 = *(const f32x4*)(red + ((size_t)(w+4)*64+lane)*4);
        f32x4 s2 = *(const f32x4*)(red + ((size_t)(w+8)*64+lane)*4);
        f32x4 s3 = *(const f32x4*)(red + ((size_t)(w+12)*64+lane)*4);
        float hy4[4];
        unsigned long long pk = 0;
#pragma unroll
        for (int r=0;r<4;r++) {
          float g  = s0[r]+s1[r]+s2[r]+s3[r] + igv[r];
          float ng = tanhf(g);
          float hy = hv[r] + iv[r]*(ng - hv[r]);
          hy4[r] = hy;
          pk |= (unsigned long long)f2b(hy) << (16*r);
        }
        f32x4 hv4; hv4[0]=hy4[0]; hv4[1]=hy4[1]; hv4[2]=hy4[2]; hv4[3]=hy4[3];
        *(f32x4*)(hFw + ((size_t)(jn>>2)*64 + bb)*4) = hv4;
        *(unsigned long long*)(hBw + (size_t)bb*Hz + jn) = pk;
        float4 ov; ov.x=hy4[0]; ov.y=hy4[1]; ov.z=hy4[2]; ov.w=hy4[3];
        *(float4*)(out + ((size_t)bb*Tz + t)*Hz + jn) = ov;
      }
      __syncthreads();                    // vmcnt drained -> stores in L2
      if (tid == 0) pubrel(canH + n, t+1);// release: wbl2 + flag (h_{t+1} visible)
    }
  }
}

// ---- final hidden state: hN[b][j] = hF(quad)[j][b]
__global__ __launch_bounds__(256)
void ktr(const float* __restrict__ hF, float* __restrict__ hN)
{
  int b = blockIdx.x;
  int j = threadIdx.x*4;
  float4 v = *(const float4*)(hF + ((size_t)(j>>2)*64 + b)*4);
  *(float4*)(hN + (size_t)b*Hz + j) = v;
}

extern "C" void kernel_launch(void* const* d_in, const int* in_sizes, int n_in,
                              void* d_out, int out_size, void* d_ws, size_t ws_size,
                              hipStream_t stream)
{
  const float* x   = (const float*)d_in[0];
  const float* h0  = (const float*)d_in[1];
  const float* ctx = (const float*)d_in[2];
  const float* Wi  = (const float*)d_in[3];
  const float* bi  = (const float*)d_in[4];
  const float* Wh  = (const float*)d_in[5];
  const float* bh  = (const float*)d_in[6];
  const float* Wp  = (const float*)d_in[7];
  const float* bp  = (const float*)d_in[8];
  const float* Wc  = (const float*)d_in[9];
  const float* bc  = (const float*)d_in[10];
  float* out = (float*)d_out;

  char* wsp = (char*)d_ws;
  float* pT  = (float*)wsp; wsp += (size_t)G3*64*sizeof(float);        // 768 KB
  float* hF0 = (float*)wsp; wsp += (size_t)Hz*64*sizeof(float);        // 256 KB
  float* hF1 = (float*)wsp; wsp += (size_t)Hz*64*sizeof(float);        // 256 KB
  float* iT  = (float*)wsp; wsp += (size_t)Hz*64*sizeof(float);        // 256 KB
  unsigned short* hB0 = (unsigned short*)wsp; wsp += (size_t)Bz*Hz*2;  // 128 KB
  unsigned short* hB1 = (unsigned short*)wsp; wsp += (size_t)Bz*Hz*2;  // 128 KB
  unsigned short* rhB = (unsigned short*)wsp; wsp += (size_t)Bz*Hz*2;  // 128 KB
  int* canP = (int*)wsp; wsp += 512;                                   // canP[64] + canH[64]
  int* canH = canP + 64;
  unsigned short* igT = (unsigned short*)wsp;                          // 96 MB

  hipMemsetAsync(canP, 0, 512, stream);
  kP  <<<dim3(G3/16),   256,  0, stream>>>(ctx, Wp, bp, bh, bc, bi, pT);
  kI  <<<dim3(64),      256,  0, stream>>>(h0, hF0, hB0);
  kAm <<<dim3(48,16),   1024, 0, stream>>>(x, Wi, pT, igT);
  krec<<<dim3(NBK),     1024, 0, stream>>>(Wh, Wc, igT, hF0, hF1, hB0, hB1, rhB, iT, out, canP, canH);
  ktr <<<dim3(64),      256,  0, stream>>>(hF0, out + (size_t)Bz*Tz*Hz);
}

// Round 8
// 4530.303 us; speedup vs baseline: 1.6084x; 1.2380x over previous
//
#include <hip/hip_runtime.h>
#include <hip/hip_bf16.h>
#include <math.h>

#define Bz 64
#define Tz 256
#define Dz 512
#define Hz 1024
#define G3 3072
#define NBK 64      // blocks in persistent recurrence kernel

typedef short bf16x8 __attribute__((ext_vector_type(8)));
typedef float f32x4 __attribute__((ext_vector_type(4)));

__device__ __forceinline__ float sigm(float x){ return 1.0f/(1.0f+expf(-x)); }

__device__ __forceinline__ unsigned short f2b(float f){
  union{float f;unsigned u;}v; v.f=f;
  unsigned r = v.u + 0x7FFFu + ((v.u>>16)&1u);
  return (unsigned short)(r>>16);
}
__device__ __forceinline__ float b2f(unsigned short s){
  union{unsigned u;float f;}v; v.u = ((unsigned)s)<<16; return v.f;
}
__device__ __forceinline__ unsigned pk2(float a, float b){
  return (unsigned)f2b(a) | ((unsigned)f2b(b)<<16);
}

// ---- hybrid coherence protocol (rounds 5+6 lessons) ----
// PRODUCER: shared-state writes via relaxed sc1 atomic stores (bypass L2 ->
//   land at memory-side LLC; nothing dirty => NO wbl2/release scan needed).
//   __syncthreads drains vmcnt, then tid0 stores the flag relaxed (r5-proven).
// CONSUMER: relaxed poll, then ONE acquire load (L1/L2 invalidate scan only
//   — no data movement) before the barrier releases the block; data then
//   moves via PLAIN cached wide vector loads (coalesced, LLC-line fetches,
//   L2 shared across co-XCD blocks) (r6-proven).
__device__ __forceinline__ void cst64(void* p, unsigned long long v){
  __hip_atomic_store((unsigned long long*)p, v, __ATOMIC_RELAXED, __HIP_MEMORY_SCOPE_AGENT);
}
__device__ __forceinline__ void cstf2(float* p, float a, float b){
  union { unsigned long long u; float2 f; } U; U.f = make_float2(a,b); cst64(p, U.u);
}
__device__ __forceinline__ int cld32(const int* p){
  return __hip_atomic_load(p, __ATOMIC_RELAXED, __HIP_MEMORY_SCOPE_AGENT);
}
__device__ __forceinline__ void cst32(int* p, int v){
  __hip_atomic_store(p, v, __ATOMIC_RELAXED, __HIP_MEMORY_SCOPE_AGENT);
}
__device__ __forceinline__ void waitcan_acq(const int* can, int tgt){
  int l = threadIdx.x & 63;
  while (!__all(cld32(can + l) >= tgt))
    __builtin_amdgcn_s_sleep(1);
  __hip_atomic_load(can + l, __ATOMIC_ACQUIRE, __HIP_MEMORY_SCOPE_AGENT);
  asm volatile("" ::: "memory");
}

// ---------------- f32 skinny GEMM core (kP only, tiny) ----------------
#define KCHUNK 128
#define LDA 132
template<int COLS, int KDIM>
__device__ __forceinline__ void gemm_core(const float* __restrict__ Abase, int rowStride,
                                          const float* __restrict__ W,
                                          int jc0, int b, int tid,
                                          float* __restrict__ acc, float* __restrict__ lds)
{
#pragma unroll
  for (int c=0;c<COLS;c++) acc[c]=0.0f;
  constexpr int C4 = KCHUNK/4;
  for (int kb=0; kb<KDIM; kb+=KCHUNK) {
    __syncthreads();
    for (int i = tid; i < Bz*C4; i += 256) {
      int r  = i / C4;
      int c4 = i % C4;
      float4 v = *(const float4*)(Abase + (size_t)r*rowStride + kb + c4*4);
      *(float4*)(lds + r*LDA + c4*4) = v;
    }
    __syncthreads();
    const float* arow  = lds + b*LDA;
    const float* wbase = W + (size_t)jc0*KDIM + kb;
    for (int k=0;k<KCHUNK;k+=4) {
      float4 a = *(const float4*)(arow + k);
#pragma unroll
      for (int c=0;c<COLS;c++) {
        float4 w = *(const float4*)(wbase + (size_t)c*KDIM + k);
        acc[c] = fmaf(a.x,w.x,fmaf(a.y,w.y,fmaf(a.z,w.z,fmaf(a.w,w.w,acc[c]))));
      }
    }
  }
}

// ---- kP: pT[j][b] = ctx[b]·Wp[j] + bp[j] + bi[j] + (j<2H ? bh[j] : bc[j-2H])
__global__ __launch_bounds__(256)
void kP(const float* __restrict__ ctx, const float* __restrict__ Wp,
        const float* __restrict__ bp, const float* __restrict__ bh,
        const float* __restrict__ bc, const float* __restrict__ bi,
        float* __restrict__ pT)
{
  __shared__ float lds[Bz*LDA];
  int tid=threadIdx.x; int b=tid&63;
  int wv=__builtin_amdgcn_readfirstlane(tid>>6);
  int jc0 = blockIdx.x*16 + wv*4;
  float acc[4];
  gemm_core<4, Hz>(ctx, Hz, Wp, jc0, b, tid, acc, lds);
#pragma unroll
  for(int c=0;c<4;c++){
    int j=jc0+c;
    float v = acc[c] + bp[j] + bi[j] + (j < 2*Hz ? bh[j] : bc[j-2*Hz]);
    pT[(size_t)j*64 + b] = v;
  }
}

// ---- kI: hF quad-layout init + hB bf16 init (parity-0 buffers). 64 blocks x 256 thr.
// hF quad layout: hF[((j>>2)*64 + b)*4 + (j&3)]
__global__ __launch_bounds__(256)
void kI(const float* __restrict__ h0, float* __restrict__ hF, unsigned short* __restrict__ hB)
{
  int b = blockIdx.x;
  int j = threadIdx.x*4;
  float4 v = *(const float4*)(h0 + (size_t)b*Hz + j);
  *(float4*)(hF + ((size_t)(j>>2)*64 + b)*4) = v;
  unsigned long long pk = (unsigned long long)pk2(v.x,v.y)
                        | ((unsigned long long)pk2(v.z,v.w) << 32);
  *(unsigned long long*)(hB + (size_t)b*Hz + j) = pk;
}

// ---- kAm: MFMA input GEMM. igT[t][j][b] = bf16( x[b,t]·Wi[j] + pT[j][b] )
__global__ __launch_bounds__(1024)
void kAm(const float* __restrict__ x, const float* __restrict__ Wi,
         const float* __restrict__ pT, unsigned short* __restrict__ igT)
{
  __shared__ unsigned short wiF[4*16*64*8];  // 64 KB
  __shared__ unsigned short xs[64*528];      // 66 KB
  __shared__ unsigned short igs[64*64];      // 8 KB
  const int tid = threadIdx.x;
  const int lane = tid & 63;
  const int w = __builtin_amdgcn_readfirstlane(tid >> 6);
  const int j0 = blockIdx.x * 64;
  const int t0 = blockIdx.y * 16;
  const int mt = w >> 2, nt = w & 3;
  const int bb = nt*16 + (lane & 15);
  const int q  = lane >> 4;
  const int jl = mt*16 + q*4;

  for (int idx = tid; idx < 4096; idx += 1024) {
    int mt2 = idx >> 10;
    int ks = (idx >> 6) & 15;
    int ln = idx & 63;
    int j = j0 + mt2*16 + (ln & 15);
    int k = ks*32 + (ln >> 4)*8;
    const float* s = Wi + (size_t)j*Dz + k;
    unsigned short* d = wiF + (size_t)idx*8;
#pragma unroll
    for (int qq=0;qq<8;qq++) d[qq] = f2b(s[qq]);
  }
  float pv[4];
#pragma unroll
  for (int r=0;r<4;r++) pv[r] = pT[(size_t)(j0+jl+r)*64 + bb];

  for (int it=0; it<16; it++) {
    int t = t0 + it;
    __syncthreads();
    for (int i = tid; i < 64*32; i += 1024) {
      int b = i >> 5, c = i & 31;
      const float* s = x + ((size_t)b*Tz + t)*Dz + c*16;
      unsigned* d = (unsigned*)(xs + (size_t)b*528 + c*16);
      float4 v0 = *(const float4*)(s);
      float4 v1 = *(const float4*)(s+4);
      float4 v2 = *(const float4*)(s+8);
      float4 v3 = *(const float4*)(s+12);
      d[0]=pk2(v0.x,v0.y); d[1]=pk2(v0.z,v0.w);
      d[2]=pk2(v1.x,v1.y); d[3]=pk2(v1.z,v1.w);
      d[4]=pk2(v2.x,v2.y); d[5]=pk2(v2.z,v2.w);
      d[6]=pk2(v3.x,v3.y); d[7]=pk2(v3.z,v3.w);
    }
    __syncthreads();
    f32x4 acc = {0.f,0.f,0.f,0.f};
    const unsigned short* bsrc = xs + (size_t)bb*528 + q*8;
#pragma unroll
    for (int ks=0; ks<16; ks++) {
      bf16x8 a = *(const bf16x8*)(wiF + ((size_t)(mt*16+ks)*64 + lane)*8);
      bf16x8 b = *(const bf16x8*)(bsrc + ks*32);
      acc = __builtin_amdgcn_mfma_f32_16x16x32_bf16(a, b, acc, 0, 0, 0);
    }
#pragma unroll
    for (int r=0;r<4;r++) igs[(size_t)(jl+r)*64 + bb] = f2b(acc[r] + pv[r]);
    __syncthreads();
    if (tid < 512) {
      int j = tid >> 3, seg = tid & 7;
      *(uint4*)(igT + ((size_t)t*G3 + j0 + j)*64 + seg*8) =
        *(const uint4*)(igs + (size_t)j*64 + seg*8);
    }
  }
}

// ---- krec: persistent MFMA recurrence, 64 blocks x 1024 threads.
// Canary sync + hybrid coherence (see helpers above):
//   producer shared-state writes: sc1 bypass stores (no wbl2 on release path)
//   consumer: poll -> acquire-inv -> plain cached vector loads
// canP[n]=t+1 after phase1@t (rhB/iT ready); canH[n]=t+1 after phase2@t (h_{t+1}).
// Phase1@t waits canH>=t; phase2@t waits canP>=t+1. hF/hB parity double-buffered;
// rhB/iT single-buffered (WAR via the canH/canP chain; max skew < 1 round).
__global__ __launch_bounds__(1024)
void krec(const float* __restrict__ Wh, const float* __restrict__ Wc,
          const unsigned short* __restrict__ igT,
          float* __restrict__ hF0, float* __restrict__ hF1,
          unsigned short* __restrict__ hB0, unsigned short* __restrict__ hB1,
          unsigned short* __restrict__ rhB, float* __restrict__ iT,
          float* __restrict__ out, int* canP, int* canH)
{
  __shared__ unsigned short whF[2*32*64*8];  // 64 KB
  __shared__ unsigned short wcF[32*64*8];    // 32 KB
  __shared__ float red[16*64*4];             // 16 KB
  const int tid = threadIdx.x;
  const int lane = tid & 63;
  const int w = __builtin_amdgcn_readfirstlane(tid >> 6);
  const int n = blockIdx.x;

  // fragment-swizzle weight slices (f32 -> bf16), one-time
  for (int idx = tid; idx < 4096; idx += 1024) {
    int mt = idx >> 11;
    int ks = (idx >> 6) & 31;
    int ln = idx & 63;
    int j = n*32 + mt*16 + (ln & 15);
    int k = ks*32 + (ln >> 4)*8;
    const float* s = Wh + (size_t)j*Hz + k;
    unsigned short* d = whF + (size_t)idx*8;
#pragma unroll
    for (int qq=0;qq<8;qq++) d[qq] = f2b(s[qq]);
  }
  for (int idx = tid; idx < 2048; idx += 1024) {
    int ks = (idx >> 6) & 31;
    int ln = idx & 63;
    int j = n*16 + (ln & 15);
    int k = ks*32 + (ln >> 4)*8;
    const float* s = Wc + (size_t)j*Hz + k;
    unsigned short* d = wcF + (size_t)idx*8;
#pragma unroll
    for (int qq=0;qq<8;qq++) d[qq] = f2b(s[qq]);
  }

  for (int t=0;t<Tz;t++) {
    const unsigned short* igt = igT + (size_t)t*G3*64;
    const unsigned short* hBr = (t&1) ? hB1 : hB0;
    unsigned short*       hBw = (t&1) ? hB0 : hB1;
    const float*          hFr = (t&1) ? hF1 : hF0;
    float*                hFw = (t&1) ? hF0 : hF1;
    // ---------- phase 1: gates r,i ----------
    {
      int tp = w & 7, kh = w >> 3;        // 8 tiles x split-K-2
      int mt = tp >> 2, nt = tp & 3;
      int bb = nt*16 + (lane & 15);
      int q  = lane >> 4;
      int jg = n*32 + mt*16 + q*4;        // gate col in [0,2048)
      float igv[4], hv[4];
      if (w < 8) {                        // igT prefetch: written pre-krec, any cached copy valid
#pragma unroll
        for (int r=0;r<4;r++) igv[r] = b2f(igt[(size_t)(jg+r)*64 + bb]);
      }
      if (w == 0) waitcan_acq(canH, t);   // h_t ready; acquire-inv before barrier release
      __syncthreads();
      if (w < 8 && n < 32) {
        f32x4 a = *(const f32x4*)(hFr + ((size_t)(jg>>2)*64 + bb)*4);
        hv[0]=a[0]; hv[1]=a[1]; hv[2]=a[2]; hv[3]=a[3];
      }
      f32x4 acc = {0.f,0.f,0.f,0.f};
      const unsigned short* bsrc = hBr + (size_t)bb*Hz + q*8;
      const unsigned short* asrc = whF + ((size_t)(mt*32 + kh*16)*64 + lane)*8;
#pragma unroll
      for (int ks=0; ks<16; ks++) {
        bf16x8 a = *(const bf16x8*)(asrc + (size_t)ks*64*8);
        bf16x8 b = *(const bf16x8*)(bsrc + (size_t)(kh*16+ks)*32);
        acc = __builtin_amdgcn_mfma_f32_16x16x32_bf16(a, b, acc, 0, 0, 0);
      }
      *(f32x4*)(red + ((size_t)w*64 + lane)*4) = acc;
      __syncthreads();
      if (w < 8) {
        f32x4 o  = *(const f32x4*)(red + ((size_t)w*64+lane)*4);
        f32x4 p2 = *(const f32x4*)(red + ((size_t)(w+8)*64+lane)*4);
        if (n < 32) {
          unsigned long long pk = 0;
#pragma unroll
          for (int r=0;r<4;r++) {
            float g = sigm(o[r] + p2[r] + igv[r]);
            pk |= (unsigned long long)f2b(g * hv[r]) << (16*r);
          }
          cst64(rhB + (size_t)bb*Hz + jg, pk);        // sc1 bypass -> LLC
        } else {
          float g0 = sigm(o[0] + p2[0] + igv[0]);
          float g1 = sigm(o[1] + p2[1] + igv[1]);
          float g2 = sigm(o[2] + p2[2] + igv[2]);
          float g3 = sigm(o[3] + p2[3] + igv[3]);
          float* ip = iT + ((size_t)((jg-1024)>>2)*64 + bb)*4;
          cstf2(ip, g0, g1); cstf2(ip+2, g2, g3);     // sc1 bypass -> LLC
        }
      }
      __syncthreads();                    // vmcnt drained -> sc1 stores at LLC
      if (tid == 0) cst32(canP + n, t+1); // relaxed flag (no wbl2 on this path)
    }
    // ---------- phase 2: n-gate + h update ----------
    {
      int nt = w & 3, kq = w >> 2;        // 4 tiles x split-K-4
      int bb = nt*16 + (lane & 15);
      int q  = lane >> 4;
      int jn = n*16 + q*4;                // col in [0,1024)
      float igv[4], hv[4], iv[4];
      if (w < 4) {                        // igT prefetch: safe pre-acquire (stale-proof)
#pragma unroll
        for (int r=0;r<4;r++) igv[r] = b2f(igt[(size_t)(2048+jn+r)*64 + bb]);
      }
      if (w == 0) waitcan_acq(canP, t+1); // rhB_t + iT_t ready; acquire-inv
      __syncthreads();
      if (w < 4) {
        f32x4 a = *(const f32x4*)(hFr + ((size_t)(jn>>2)*64 + bb)*4);
        hv[0]=a[0]; hv[1]=a[1]; hv[2]=a[2]; hv[3]=a[3];
        f32x4 b = *(const f32x4*)(iT + ((size_t)(jn>>2)*64 + bb)*4);
        iv[0]=b[0]; iv[1]=b[1]; iv[2]=b[2]; iv[3]=b[3];
      }
      f32x4 acc = {0.f,0.f,0.f,0.f};
      const unsigned short* bsrc = rhB + (size_t)bb*Hz + q*8;
#pragma unroll
      for (int ks=0; ks<8; ks++) {
        bf16x8 a = *(const bf16x8*)(wcF + ((size_t)(kq*8+ks)*64 + lane)*8);
        bf16x8 b = *(const bf16x8*)(bsrc + (size_t)(kq*8+ks)*32);
        acc = __builtin_amdgcn_mfma_f32_16x16x32_bf16(a, b, acc, 0, 0, 0);
      }
      *(f32x4*)(red + ((size_t)w*64 + lane)*4) = acc;
      __syncthreads();
      if (w < 4) {
        f32x4 s0 = *(const f32x4*)(red + ((size_t)w*64+lane)*4);
        f32x4 s1 = *(const f32x4*)(red + ((size_t)(w+4)*64+lane)*4);
        f32x4 s2 = *(const f32x4*)(red + ((size_t)(w+8)*64+lane)*4);
        f32x4 s3 = *(const f32x4*)(red + ((size_t)(w+12)*64+lane)*4);
        float hy4[4];
        unsigned long long pk = 0;
#pragma unroll
        for (int r=0;r<4;r++) {
          float g  = s0[r]+s1[r]+s2[r]+s3[r] + igv[r];
          float ng = tanhf(g);
          float hy = hv[r] + iv[r]*(ng - hv[r]);
          hy4[r] = hy;
          pk |= (unsigned long long)f2b(hy) << (16*r);
        }
        float* hp = hFw + ((size_t)(jn>>2)*64 + bb)*4;
        cstf2(hp,   hy4[0], hy4[1]);                  // sc1 bypass -> LLC
        cstf2(hp+2, hy4[2], hy4[3]);
        cst64(hBw + (size_t)bb*Hz + jn, pk);          // sc1 bypass -> LLC
        float4 ov; ov.x=hy4[0]; ov.y=hy4[1]; ov.z=hy4[2]; ov.w=hy4[3];
        *(float4*)(out + ((size_t)bb*Tz + t)*Hz + jn) = ov;  // plain (host-only)
      }
      __syncthreads();                    // vmcnt drained -> sc1 stores at LLC
      if (tid == 0) cst32(canH + n, t+1); // relaxed flag
    }
  }
}

// ---- final hidden state: hN[b][j] = hF(quad)[j][b]
__global__ __launch_bounds__(256)
void ktr(const float* __restrict__ hF, float* __restrict__ hN)
{
  int b = blockIdx.x;
  int j = threadIdx.x*4;
  float4 v = *(const float4*)(hF + ((size_t)(j>>2)*64 + b)*4);
  *(float4*)(hN + (size_t)b*Hz + j) = v;
}

extern "C" void kernel_launch(void* const* d_in, const int* in_sizes, int n_in,
                              void* d_out, int out_size, void* d_ws, size_t ws_size,
                              hipStream_t stream)
{
  const float* x   = (const float*)d_in[0];
  const float* h0  = (const float*)d_in[1];
  const float* ctx = (const float*)d_in[2];
  const float* Wi  = (const float*)d_in[3];
  const float* bi  = (const float*)d_in[4];
  const float* Wh  = (const float*)d_in[5];
  const float* bh  = (const float*)d_in[6];
  const float* Wp  = (const float*)d_in[7];
  const float* bp  = (const float*)d_in[8];
  const float* Wc  = (const float*)d_in[9];
  const float* bc  = (const float*)d_in[10];
  float* out = (float*)d_out;

  char* wsp = (char*)d_ws;
  float* pT  = (float*)wsp; wsp += (size_t)G3*64*sizeof(float);        // 768 KB
  float* hF0 = (float*)wsp; wsp += (size_t)Hz*64*sizeof(float);        // 256 KB
  float* hF1 = (float*)wsp; wsp += (size_t)Hz*64*sizeof(float);        // 256 KB
  float* iT  = (float*)wsp; wsp += (size_t)Hz*64*sizeof(float);        // 256 KB
  unsigned short* hB0 = (unsigned short*)wsp; wsp += (size_t)Bz*Hz*2;  // 128 KB
  unsigned short* hB1 = (unsigned short*)wsp; wsp += (size_t)Bz*Hz*2;  // 128 KB
  unsigned short* rhB = (unsigned short*)wsp; wsp += (size_t)Bz*Hz*2;  // 128 KB
  int* canP = (int*)wsp; wsp += 512;                                   // canP[64] + canH[64]
  int* canH = canP + 64;
  unsigned short* igT = (unsigned short*)wsp;                          // 96 MB

  hipMemsetAsync(canP, 0, 512, stream);
  kP  <<<dim3(G3/16),   256,  0, stream>>>(ctx, Wp, bp, bh, bc, bi, pT);
  kI  <<<dim3(64),      256,  0, stream>>>(h0, hF0, hB0);
  kAm <<<dim3(48,16),   1024, 0, stream>>>(x, Wi, pT, igT);
  krec<<<dim3(NBK),     1024, 0, stream>>>(Wh, Wc, igT, hF0, hF1, hB0, hB1, rhB, iT, out, canP, canH);
  ktr <<<dim3(64),      256,  0, stream>>>(hF0, out + (size_t)Bz*Tz*Hz);
}